// Round 14
// baseline (208.618 us; speedup 1.0000x reference)
//
#include <hip/hip_runtime.h>

static constexpr int NW = 20000, NT = 2000, ND = 5000;
static constexpr int E_WW = 150000, E_WT = 80000, E_WD = 80000, E_TT = 20000, E_TD = 40000;

typedef short bf16x8 __attribute__((ext_vector_type(8)));
typedef float f32x4 __attribute__((ext_vector_type(4)));
typedef float f32x2 __attribute__((ext_vector_type(2)));

__device__ __forceinline__ unsigned short f2bf(float f) {
  union { float f; unsigned int u; } c; c.f = f;
  unsigned int u = c.u;
  u += 0x7fffu + ((u >> 16) & 1u);
  return (unsigned short)(u >> 16);
}
__device__ __forceinline__ float bf2f(unsigned short h) {
  union { unsigned int u; float f; } c; c.u = ((unsigned int)h) << 16; return c.f;
}
__device__ __forceinline__ bf16x8 pack8(float4 a, float4 b) {
  bf16x8 r;
  r[0] = (short)f2bf(a.x); r[1] = (short)f2bf(a.y); r[2] = (short)f2bf(a.z); r[3] = (short)f2bf(a.w);
  r[4] = (short)f2bf(b.x); r[5] = (short)f2bf(b.y); r[6] = (short)f2bf(b.z); r[7] = (short)f2bf(b.w);
  return r;
}
__device__ __forceinline__ unsigned char f2fp8(float x) {
  int p = __builtin_amdgcn_cvt_pk_fp8_f32(x, x, 0, false);
  return (unsigned char)(p & 0xff);
}

// ---------------- CSR descriptor ----------------
struct CsrDesc {
  const int* dst[5];
  const int* src[5];
  int E[5], N[5], cbase[5];
};

// ================= PREP mega-kernel: pack7 | wq_eff | pack_headw | hist =================
struct PrepArgs {
  const float* psrc[7]; unsigned short* pdst[7];
  const float* wq[5]; const float* bqp[5];
  unsigned short* qdst[5];
  float* beff;
  const float* att;
  const float* msg; unsigned short* wvp;
  CsrDesc dsc;
  int* counts;
  int bEff, bHw, bHist, bTot;
};
__global__ __launch_bounds__(256) void prep_kernel(PrepArgs a) {
  __shared__ float tile[32][33];
  int b = blockIdx.x;
  int tid = threadIdx.x;
  if (b < a.bEff) {
    int m = b >> 6, bk = ((b >> 3) & 7) * 32, bn = (b & 7) * 32;
    const float* W = a.psrc[m];
    unsigned short* WT = a.pdst[m];
    int tx = tid & 31, ty = tid >> 5;
#pragma unroll
    for (int i = 0; i < 32; i += 8)
      tile[ty + i][tx] = W[(size_t)(bk + ty + i) * 256 + bn + tx];
    __syncthreads();
#pragma unroll
    for (int i = 0; i < 32; i += 8)
      WT[(size_t)(bn + ty + i) * 256 + bk + tx] = f2bf(tile[tx][ty + i]);
  } else if (b < a.bHw) {
    int t = (b - a.bEff) * 256 + tid;
    if (t < 5 * 65536) {
      int r = t >> 16, rem = t & 65535;
      int n = rem >> 8, kk = rem & 255;
      int h = n >> 5, j = n & 31;
      const float* wrow = a.wq[r] + kk * 256 + h * 32;
      const float* arow = a.att + r * 8192 + h * 1024 + j * 32;
      float s = 0.f;
#pragma unroll
      for (int d = 0; d < 32; d += 4) {
        float4 wv = *(const float4*)(wrow + d);
        float4 av = *(const float4*)(arow + d);
        s += wv.x * av.x + wv.y * av.y + wv.z * av.z + wv.w * av.w;
      }
      a.qdst[r][n * 256 + kk] = f2bf(s);
    } else {
      int idx = t - 5 * 65536;
      if (idx < 1280) {
        int r = idx >> 8, n = idx & 255;
        int h = n >> 5, j = n & 31;
        const float* brow = a.bqp[r] + h * 32;
        const float* arow = a.att + r * 8192 + h * 1024 + j * 32;
        float s = 0.f;
#pragma unroll
        for (int d = 0; d < 32; d += 4) {
          float4 bv = *(const float4*)(brow + d);
          float4 av = *(const float4*)(arow + d);
          s += bv.x * av.x + bv.y * av.y + bv.z * av.z + bv.w * av.w;
        }
        a.beff[r * 256 + n] = s;
      }
    }
  } else if (b < a.bHist) {
    int t = (b - a.bHw) * 256 + tid;
    if (t < 5 * 8192) {
      int m = t >> 13, rem = t & 8191;
      int hc = rem >> 9, idx = rem & 511;
      int lane = idx >> 3, j = idx & 7;
      int h = hc >> 1, c = hc & 1;
      int k = (lane >> 4) * 8 + j, n = c * 16 + (lane & 15);
      a.wvp[t] = f2bf(a.msg[(size_t)m * 8192 + h * 1024 + k * 32 + n]);
    }
  } else {
    int t = (b - a.bHist) * 256 + tid;
    int r = 0, base = 0;
    while (r < 5 && t >= base + a.dsc.E[r]) { base += a.dsc.E[r]; r++; }
    if (r >= 5) return;
    int e = t - base;
    atomicAdd(a.counts + a.dsc.cbase[r] + a.dsc.dst[r][e], 1);
  }
}

// ================= projection GEMM v6: 64x256 tiles + XCD swizzle =====================
// One block per (64-row tile, 256-col group); per wave 16 rows x 256 cols (16 MFMA/A-frag).
// A f32 converted in staging (once per element per col-group). LDS 40 KB -> 4 blocks/CU.
struct ProjAll {
  const float* A[3];
  const unsigned short* WT[3];
  const float* bias[3][4];
  unsigned char* outB[3][4];
  int esz[3][4];
  int M[3], R[3], C[3], segBase[4];
  const int* counts; int* offsets; int scanN;   // embedded scan block
};
__global__ __launch_bounds__(256) void proj_all(ProjAll pa) {
  __shared__ unsigned short As[64 * 64];    // 8 KB
  __shared__ unsigned short Bs[256 * 64];   // 32 KB
  __shared__ int wpart2[4];
  __shared__ int carry2;
  const int tid = threadIdx.x;
  if ((int)blockIdx.x >= pa.segBase[3]) {
    // ---- embedded serial scan over concatenated counts ----
    int lane = tid & 63, w = tid >> 6;
    if (tid == 0) carry2 = 0;
    __syncthreads();
    const int N = pa.scanN;
    for (int base = 0; base < N; base += 1024) {
      int idx = base + tid * 4;
      int v0 = 0, v1 = 0, v2 = 0, v3 = 0;
      if (idx + 3 < N) {
        int4 t4 = *(const int4*)(pa.counts + idx);
        v0 = t4.x; v1 = t4.y; v2 = t4.z; v3 = t4.w;
      } else if (idx < N) {
        v0 = pa.counts[idx];
        if (idx + 1 < N) v1 = pa.counts[idx + 1];
        if (idx + 2 < N) v2 = pa.counts[idx + 2];
      }
      int ts = v0 + v1 + v2 + v3;
      int x = ts;
#pragma unroll
      for (int d = 1; d < 64; d <<= 1) {
        int t = __shfl_up(x, d, 64);
        if (lane >= d) x += t;
      }
      if (lane == 63) wpart2[w] = x;
      __syncthreads();
      if (tid == 0) {
        int s = 0;
#pragma unroll
        for (int j = 0; j < 4; j++) { int t = wpart2[j]; wpart2[j] = s; s += t; }
      }
      __syncthreads();
      int excl = carry2 + wpart2[w] + (x - ts);
      if (idx < N)     pa.offsets[idx]     = excl;
      if (idx + 1 < N) pa.offsets[idx + 1] = excl + v0;
      if (idx + 2 < N) pa.offsets[idx + 2] = excl + v0 + v1;
      if (idx + 3 < N) pa.offsets[idx + 3] = excl + v0 + v1 + v2;
      __syncthreads();
      if (tid == 255) carry2 = excl + ts;
      __syncthreads();
    }
    if (tid == 0) pa.offsets[N] = carry2;
    return;
  }
  int nt = 0;
  while (nt < 2 && (int)blockIdx.x >= pa.segBase[nt + 1]) nt++;
  int local = blockIdx.x - pa.segBase[nt];
  const int C = pa.C[nt];
  const int xcd = local & 7, slot = local >> 3;
  const int rt = xcd + 8 * (slot / C);
  const int cg = slot % C;
  if (rt >= pa.R[nt]) return;
  const int bm = rt * 64;
  const float* A = pa.A[nt];
  const unsigned short* WT = pa.WT[nt] + (size_t)cg * 65536;  // cg-th 256-row group of WT
  const int M = pa.M[nt];
  const int wave = tid >> 6, lane = tid & 63;
  f32x4 acc[16] = {};
  const int ar = wave * 16 + (lane & 15);
  const int swz = lane & 7;
  for (int k0 = 0; k0 < 256; k0 += 64) {
    // A stage (f32 -> bf16)
#pragma unroll
    for (int i = 0; i < 2; i++) {
      int c = tid + i * 256;
      int row = c >> 3, sl = c & 7;
      int srow = bm + row;
      float4 a0 = make_float4(0.f, 0.f, 0.f, 0.f), a1 = a0;
      if (srow < M) {
        a0 = *(const float4*)(A + (size_t)srow * 256 + k0 + sl * 8);
        a1 = *(const float4*)(A + (size_t)srow * 256 + k0 + sl * 8 + 4);
      }
      *(bf16x8*)&As[row * 64 + (sl ^ (row & 7)) * 8] = pack8(a0, a1);
    }
    // B stage (256 out-cols x 64 k)
#pragma unroll
    for (int i = 0; i < 8; i++) {
      int c = tid + i * 256;
      int row = c >> 3, sl = c & 7;
      bf16x8 bv = *(const bf16x8*)(WT + (size_t)row * 256 + k0 + sl * 8);
      *(bf16x8*)&Bs[row * 64 + (sl ^ (row & 7)) * 8] = bv;
    }
    __syncthreads();
#pragma unroll
    for (int kk = 0; kk < 2; kk++) {
      int slot2 = kk * 4 + (lane >> 4);
      bf16x8 av = *(const bf16x8*)&As[ar * 64 + ((slot2 ^ swz) * 8)];
#pragma unroll
      for (int nf = 0; nf < 16; nf++) {
        int br = nf * 16 + (lane & 15);
        bf16x8 bv = *(const bf16x8*)&Bs[br * 64 + ((slot2 ^ swz) * 8)];
        acc[nf] = __builtin_amdgcn_mfma_f32_16x16x32_bf16(av, bv, acc[nf], 0, 0, 0);
      }
    }
    __syncthreads();
  }
  const int col = lane & 15;
  const float* bias = pa.bias[nt][cg];
  unsigned char* outB = pa.outB[nt][cg];
  const int esz = pa.esz[nt][cg];
#pragma unroll
  for (int nf = 0; nf < 16; nf++) {
    float bsv = bias[nf * 16 + col];
    int idx = nf * 16 + col;
#pragma unroll
    for (int rr = 0; rr < 4; rr++) {
      int row = bm + wave * 16 + (lane >> 4) * 4 + rr;
      if (row < M) {
        float v = acc[nf][rr] + bsv;
        if (esz == 2) *(unsigned short*)(outB + (size_t)row * 512 + idx * 2) = f2bf(v);
        else          outB[(size_t)row * 512 + idx] = f2fp8(v);
      }
    }
  }
}

// ================= scatter =================
__global__ void scatter5(CsrDesc d, const int* __restrict__ offsets, int* __restrict__ cursor,
                         int* __restrict__ ssrc) {
  int t = blockIdx.x * blockDim.x + threadIdx.x;
  int r = 0, base = 0;
  while (r < 5 && t >= base + d.E[r]) { base += d.E[r]; r++; }
  if (r >= 5) return;
  int e = t - base;
  int dn = d.dst[r][e];
  int pos = offsets[d.cbase[r] + dn] + atomicAdd(cursor + d.cbase[r] + dn, 1);
  ssrc[pos] = d.src[r][e];
}

// ================= fused attention + online softmax + fp8 k/v aggregation =================
struct AttArgs {
  const unsigned short* qh[5]; const unsigned char* kv8[5];
  const int* offs[5]; unsigned short* agg[5];
  const int* ssrc;
  const float* pri;
  int bcum[6]; int Ndst[5];
};
__global__ __launch_bounds__(256) void fused_att_agg(AttArgs a) {
  int r = 0;
  while (r < 4 && (int)blockIdx.x >= a.bcum[r + 1]) r++;
  int wave = threadIdx.x >> 6, lane = threadIdx.x & 63;
  int node = (blockIdx.x - a.bcum[r]) * 4 + wave;
  if (node >= a.Ndst[r]) return;
  const unsigned short* qh = a.qh[r];
  const unsigned char* kvb = a.kv8[r];
  const int* ssrc = a.ssrc;
  const int* offs = a.offs[r];
  int h = lane >> 3;
  float prih = a.pri[r * 8 + h] * 0.17677669529663687f;  // pri/sqrt(32)
  int r0 = offs[node], r1 = offs[node + 1];
  float4 acc = make_float4(0.f, 0.f, 0.f, 0.f);
  if (r0 < r1) {
    ushort4 qv = *(const ushort4*)(qh + (size_t)node * 256 + lane * 4);
    float q0 = bf2f(qv.x), q1 = bf2f(qv.y), q2 = bf2f(qv.z), q3 = bf2f(qv.w);
    float m = -1e30f, s = 0.f;
    for (int i = r0; i < r1; i += 2) {
      int sA = ssrc[i];
      bool two = (i + 1 < r1);
      int sB = two ? ssrc[i + 1] : sA;
      const unsigned char* pA = kvb + (size_t)sA * 512 + lane * 4;
      const unsigned char* pB = kvb + (size_t)sB * 512 + lane * 4;
      unsigned int kuA = *(const unsigned int*)pA;
      unsigned int kuB = *(const unsigned int*)pB;
      unsigned int vuA = *(const unsigned int*)(pA + 256);
      unsigned int vuB = *(const unsigned int*)(pB + 256);
      f32x2 ka01 = __builtin_amdgcn_cvt_pk_f32_fp8((int)kuA, false);
      f32x2 ka23 = __builtin_amdgcn_cvt_pk_f32_fp8((int)kuA, true);
      f32x2 kb01 = __builtin_amdgcn_cvt_pk_f32_fp8((int)kuB, false);
      f32x2 kb23 = __builtin_amdgcn_cvt_pk_f32_fp8((int)kuB, true);
      float dA = q0 * ka01[0] + q1 * ka01[1] + q2 * ka23[0] + q3 * ka23[1];
      float dB = q0 * kb01[0] + q1 * kb01[1] + q2 * kb23[0] + q3 * kb23[1];
      dA += __shfl_xor(dA, 1, 64); dB += __shfl_xor(dB, 1, 64);
      dA += __shfl_xor(dA, 2, 64); dB += __shfl_xor(dB, 2, 64);
      dA += __shfl_xor(dA, 4, 64); dB += __shfl_xor(dB, 4, 64);
      float lA = dA * prih;
      float lB = two ? dB * prih : -1e30f;
      float mn = fmaxf(m, fmaxf(lA, lB));
      float sc = __expf(m - mn);
      float wA = __expf(lA - mn);
      float wB = __expf(lB - mn);
      m = mn;
      s = s * sc + wA + wB;
      f32x2 va01 = __builtin_amdgcn_cvt_pk_f32_fp8((int)vuA, false);
      f32x2 va23 = __builtin_amdgcn_cvt_pk_f32_fp8((int)vuA, true);
      f32x2 vb01 = __builtin_amdgcn_cvt_pk_f32_fp8((int)vuB, false);
      f32x2 vb23 = __builtin_amdgcn_cvt_pk_f32_fp8((int)vuB, true);
      acc.x = acc.x * sc + wA * va01[0] + wB * vb01[0];
      acc.y = acc.y * sc + wA * va01[1] + wB * vb01[1];
      acc.z = acc.z * sc + wA * va23[0] + wB * vb23[0];
      acc.w = acc.w * sc + wA * va23[1] + wB * vb23[1];
    }
    float inv = 1.f / fmaxf(s, 1e-9f);
    acc.x *= inv; acc.y *= inv; acc.z *= inv; acc.w *= inv;
  }
  ushort4 o;
  o.x = f2bf(acc.x); o.y = f2bf(acc.y); o.z = f2bf(acc.z); o.w = f2bf(acc.w);
  *(ushort4*)(a.agg[r] + (size_t)node * 256 + lane * 4) = o;
}

// ================= msg transform + relu + cross-etype mean -> t bf16 =================
struct MsgArgs {
  const unsigned short* aggA[3]; const unsigned short* aggB[3];
  const unsigned short* fA[3]; const unsigned short* fB[3];
  unsigned short* t[3];
  float scale[3];
  int N[3]; int bcum[4];
};
__global__ __launch_bounds__(256) void msg_transform_all(MsgArgs a) {
  int g = 0;
  while (g < 2 && (int)blockIdx.x >= a.bcum[g + 1]) g++;
  int local = blockIdx.x - a.bcum[g];
  const unsigned short* aggA = a.aggA[g];
  const unsigned short* aggB = a.aggB[g];
  const unsigned short* fA = a.fA[g];
  const unsigned short* fB = a.fB[g];
  unsigned short* t = a.t[g];
  float scale = a.scale[g];
  int N = a.N[g];
  int wave = threadIdx.x >> 6, lane = threadIdx.x & 63;
  int r0 = local * 64 + wave * 16;
  int arow = r0 + (lane & 15);
  bool valid = arow < N;
  int kofs = (lane >> 4) * 8;
  f32x4 z{};
#pragma unroll
  for (int h = 0; h < 8; h++) {
    bf16x8 aA{}, aB{};
    if (valid) {
      aA = *(const bf16x8*)(aggA + (size_t)arow * 256 + h * 32 + kofs);
      if (aggB) aB = *(const bf16x8*)(aggB + (size_t)arow * 256 + h * 32 + kofs);
    }
#pragma unroll
    for (int c = 0; c < 2; c++) {
      bf16x8 bA = *(const bf16x8*)(fA + ((h * 2 + c) * 64 + lane) * 8);
      f32x4 oA = __builtin_amdgcn_mfma_f32_16x16x32_bf16(aA, bA, z, 0, 0, 0);
      f32x4 oB = z;
      if (aggB) {
        bf16x8 bB = *(const bf16x8*)(fB + ((h * 2 + c) * 64 + lane) * 8);
        oB = __builtin_amdgcn_mfma_f32_16x16x32_bf16(aB, bB, z, 0, 0, 0);
      }
      int colc = h * 32 + c * 16 + (lane & 15);
#pragma unroll
      for (int rr = 0; rr < 4; rr++) {
        int row = r0 + (lane >> 4) * 4 + rr;
        if (row < N) {
          float v = fmaxf(oA[rr], 0.f) + fmaxf(oB[rr], 0.f);
          t[(size_t)row * 256 + colc] = f2bf(v * scale);
        }
      }
    }
  }
}

// ================= unified output GEMM + skip-blend + LayerNorm =================
struct OutAll {
  const unsigned short* tA[3]; const unsigned short* WT[3];
  const float* ba[3]; const float* feat[3];
  const float* gamma[3]; const float* beta[3];
  float* op[3];
  int M[3], bcum[4];
  const float* skipv;
};
__global__ __launch_bounds__(256) void out_all_ln(OutAll oa) {
  __shared__ unsigned short As[64 * 64];
  __shared__ unsigned short Bs[256 * 64];
  int g = 0;
  while (g < 2 && (int)blockIdx.x >= oa.bcum[g + 1]) g++;
  const int bm = (blockIdx.x - oa.bcum[g]) * 64;
  const unsigned short* tA = oa.tA[g];
  const unsigned short* WT = oa.WT[g];
  const int M = oa.M[g];
  const int tid = threadIdx.x, wave = tid >> 6, lane = tid & 63;
  f32x4 acc[16] = {};
  const int ar = wave * 16 + (lane & 15);
  const int swz = lane & 7;
  for (int k0 = 0; k0 < 256; k0 += 64) {
#pragma unroll
    for (int i = 0; i < 2; i++) {
      int c = tid + i * 256;
      int row = c >> 3, sl = c & 7;
      int srow = bm + row;
      bf16x8 av{};
      if (srow < M) av = *(const bf16x8*)(tA + (size_t)srow * 256 + k0 + sl * 8);
      *(bf16x8*)&As[row * 64 + (sl ^ (row & 7)) * 8] = av;
    }
#pragma unroll
    for (int i = 0; i < 8; i++) {
      int c = tid + i * 256;
      int row = c >> 3, sl = c & 7;
      bf16x8 bv = *(const bf16x8*)(WT + (size_t)row * 256 + k0 + sl * 8);
      *(bf16x8*)&Bs[row * 64 + (sl ^ (row & 7)) * 8] = bv;
    }
    __syncthreads();
#pragma unroll
    for (int kk = 0; kk < 2; kk++) {
      int slot = kk * 4 + (lane >> 4);
      bf16x8 av = *(const bf16x8*)&As[ar * 64 + ((slot ^ swz) * 8)];
#pragma unroll
      for (int nf = 0; nf < 16; nf++) {
        int br = nf * 16 + (lane & 15);
        bf16x8 bv = *(const bf16x8*)&Bs[br * 64 + ((slot ^ swz) * 8)];
        acc[nf] = __builtin_amdgcn_mfma_f32_16x16x32_bf16(av, bv, acc[nf], 0, 0, 0);
      }
    }
    __syncthreads();
  }
  const int c16 = lane & 15;
  float a_skip = 1.f / (1.f + __expf(-oa.skipv[g]));
  float one_m = 1.f - a_skip;
  const float* gamma = oa.gamma[g];
  const float* beta = oa.beta[g];
  const float* ba = oa.ba[g];
  const float* feat = oa.feat[g];
  float* outp = oa.op[g];
  float gg[16], bb[16], bia[16];
#pragma unroll
  for (int nf = 0; nf < 16; nf++) {
    gg[nf] = gamma[nf * 16 + c16];
    bb[nf] = beta[nf * 16 + c16];
    bia[nf] = ba[nf * 16 + c16];
  }
#pragma unroll
  for (int rr = 0; rr < 4; rr++) {
    int row = bm + wave * 16 + (lane >> 4) * 4 + rr;
    bool valid = row < M;
#pragma unroll
    for (int nf = 0; nf < 16; nf++) {
      float fv = valid ? feat[(size_t)row * 256 + nf * 16 + c16] : 0.f;
      acc[nf][rr] = (acc[nf][rr] + bia[nf]) * a_skip + fv * one_m;
    }
    float p = 0.f;
#pragma unroll
    for (int nf = 0; nf < 16; nf++) p += acc[nf][rr];
    p += __shfl_xor(p, 1, 16); p += __shfl_xor(p, 2, 16);
    p += __shfl_xor(p, 4, 16); p += __shfl_xor(p, 8, 16);
    float mu = p * (1.f / 256.f);
    float qv = 0.f;
#pragma unroll
    for (int nf = 0; nf < 16; nf++) { float dd = acc[nf][rr] - mu; qv += dd * dd; }
    qv += __shfl_xor(qv, 1, 16); qv += __shfl_xor(qv, 2, 16);
    qv += __shfl_xor(qv, 4, 16); qv += __shfl_xor(qv, 8, 16);
    float rstd = rsqrtf(qv * (1.f / 256.f) + 1e-5f);
    if (valid) {
#pragma unroll
      for (int nf = 0; nf < 16; nf++)
        outp[(size_t)row * 256 + nf * 16 + c16] = (acc[nf][rr] - mu) * rstd * gg[nf] + bb[nf];
    }
  }
}

extern "C" void kernel_launch(void* const* d_in, const int* in_sizes, int n_in,
                              void* d_out, int out_size, void* d_ws, size_t ws_size,
                              hipStream_t stream) {
  const float* feat_w = (const float*)d_in[0];
  const float* feat_t = (const float*)d_in[1];
  const float* feat_d = (const float*)d_in[2];
  const float* Wk = (const float*)d_in[3];
  const float* bk = (const float*)d_in[4];
  const float* Wq = (const float*)d_in[5];
  const float* bq = (const float*)d_in[6];
  const float* Wv = (const float*)d_in[7];
  const float* bv = (const float*)d_in[8];
  const float* Wa = (const float*)d_in[9];
  const float* ba = (const float*)d_in[10];
  const float* ln_scale = (const float*)d_in[11];
  const float* ln_bias = (const float*)d_in[12];
  const float* skip = (const float*)d_in[13];
  const float* rel_pri = (const float*)d_in[14];
  const float* rel_att = (const float*)d_in[15];
  const float* rel_msg = (const float*)d_in[16];
  const int* src_ww = (const int*)d_in[17];
  const int* dst_ww = (const int*)d_in[18];
  const int* src_wt = (const int*)d_in[19];
  const int* dst_wt = (const int*)d_in[20];
  const int* src_wd = (const int*)d_in[21];
  const int* dst_wd = (const int*)d_in[22];
  const int* src_tt = (const int*)d_in[23];
  const int* dst_tt = (const int*)d_in[24];
  const int* src_td = (const int*)d_in[25];
  const int* dst_td = (const int*)d_in[26];
  float* out = (float*)d_out;
  float* ws = (float*)d_ws;

  // ---- workspace (sizes in FLOAT units) ----
  size_t off = 0;
  auto allocF = [&](size_t nf) { float* p = ws + off; off += nf; return p; };
  unsigned char* kv_w = (unsigned char*)allocF(2560000);   // [20000][512B] fp8 k|v
  unsigned char* kv_t = (unsigned char*)allocF(256000);    // [2000][512B]
  unsigned short* qhat0 = (unsigned short*)allocF(2560000);
  unsigned short* qhat1 = (unsigned short*)allocF(256000);
  unsigned short* qhat2 = (unsigned short*)allocF(640000);
  unsigned short* qhat3 = (unsigned short*)allocF(256000);
  unsigned short* qhat4 = (unsigned short*)allocF(640000);
  unsigned short* aggr0 = (unsigned short*)allocF(2560000);
  unsigned short* aggr1 = (unsigned short*)allocF(256000);
  unsigned short* aggr2 = (unsigned short*)allocF(640000);
  unsigned short* aggr3 = (unsigned short*)allocF(256000);
  unsigned short* aggr4 = (unsigned short*)allocF(640000);
  unsigned short* t_word  = (unsigned short*)allocF(2560000);
  unsigned short* t_topic = (unsigned short*)allocF(256000);
  unsigned short* t_doc   = (unsigned short*)allocF(640000);
  unsigned short* WTw = (unsigned short*)allocF(98304);   // [768][256]:  qeff0 | k | v
  unsigned short* WTt = (unsigned short*)allocF(131072);  // [1024][256]: k | v | qeff1 | qeff3
  unsigned short* WTd = (unsigned short*)allocF(65536);   // [512][256]:  qeff2 | qeff4
  unsigned short* WTa = (unsigned short*)allocF(98304);   // 3 x 256x256
  unsigned short* wvp = (unsigned short*)allocF(20480);   // msg frag-packed
  float* bq_eff = allocF(1280);                           // 5 x 256 f32
  int* counts  = (int*)allocF(34000);
  int* cursor  = (int*)allocF(34000);
  int* offsets = (int*)allocF(34004);
  int* ssrc    = (int*)allocF(370000);

  dim3 b256(256);
  auto cdiv = [](int a, int b) { return (a + b - 1) / b; };

  // ---- CSR descriptor ----
  CsrDesc dsc;
  dsc.dst[0] = dst_ww; dsc.dst[1] = dst_wt; dsc.dst[2] = dst_wd; dsc.dst[3] = dst_tt; dsc.dst[4] = dst_td;
  dsc.src[0] = src_ww; dsc.src[1] = src_wt; dsc.src[2] = src_wd; dsc.src[3] = src_tt; dsc.src[4] = src_td;
  int Es[5] = {E_WW, E_WT, E_WD, E_TT, E_TD};
  int Ns[5] = {NW, NT, ND, NT, ND};
  int cb = 0;
  for (int r = 0; r < 5; r++) {
    dsc.E[r] = Es[r]; dsc.N[r] = Ns[r]; dsc.cbase[r] = cb;
    cb += Ns[r];
  }

  hipMemsetAsync(counts, 0, (size_t)68000 * sizeof(int), stream);  // counts + cursor

  // ---- prep mega-kernel ----
  {
    PrepArgs pr;
    pr.psrc[0] = Wk;           pr.pdst[0] = WTw + 65536;    // word k
    pr.psrc[1] = Wv;           pr.pdst[1] = WTw + 131072;   // word v
    pr.psrc[2] = Wk + 65536;   pr.pdst[2] = WTt;            // topic k
    pr.psrc[3] = Wv + 65536;   pr.pdst[3] = WTt + 65536;    // topic v
    pr.psrc[4] = Wa;           pr.pdst[4] = WTa;
    pr.psrc[5] = Wa + 65536;   pr.pdst[5] = WTa + 65536;
    pr.psrc[6] = Wa + 131072;  pr.pdst[6] = WTa + 131072;
    pr.wq[0] = Wq;           pr.bqp[0] = bq;        pr.qdst[0] = WTw;            // ww
    pr.wq[1] = Wq + 65536;   pr.bqp[1] = bq + 256;  pr.qdst[1] = WTt + 131072;   // wt
    pr.wq[2] = Wq + 131072;  pr.bqp[2] = bq + 512;  pr.qdst[2] = WTd;            // wd
    pr.wq[3] = Wq + 65536;   pr.bqp[3] = bq + 256;  pr.qdst[3] = WTt + 196608;   // tt
    pr.wq[4] = Wq + 131072;  pr.bqp[4] = bq + 512;  pr.qdst[4] = WTd + 65536;    // td
    pr.beff = bq_eff;
    pr.att = rel_att;
    pr.msg = rel_msg; pr.wvp = wvp;
    pr.dsc = dsc; pr.counts = counts;
    int nPack = 7 * 64;                         // 448
    int nEff  = cdiv(5 * 65536 + 1280, 256);    // 1285
    int nHw   = cdiv(5 * 8192, 256);            // 160
    int nHist = cdiv(370000, 256);              // 1446
    pr.bEff  = nPack;
    pr.bHw   = nPack + nEff;
    pr.bHist = nPack + nEff + nHw;
    pr.bTot  = nPack + nEff + nHw + nHist;
    prep_kernel<<<pr.bTot, b256, 0, stream>>>(pr);
  }

  // ---- projections v6 (64x256 tiles, XCD swizzle, + scan block) ----
  {
    ProjAll pa;
    pa.A[0] = feat_w; pa.A[1] = feat_t; pa.A[2] = feat_d;
    pa.WT[0] = WTw;   pa.WT[1] = WTt;   pa.WT[2] = WTd;
    pa.M[0] = NW; pa.M[1] = NT; pa.M[2] = ND;
    // word col-groups: qeff0 (bf16) | k (fp8) | v (fp8)
    pa.bias[0][0] = bq_eff;       pa.outB[0][0] = (unsigned char*)qhat0; pa.esz[0][0] = 2;
    pa.bias[0][1] = bk;           pa.outB[0][1] = kv_w;                  pa.esz[0][1] = 1;
    pa.bias[0][2] = bv;           pa.outB[0][2] = kv_w + 256;            pa.esz[0][2] = 1;
    pa.bias[0][3] = bq_eff;       pa.outB[0][3] = (unsigned char*)qhat0; pa.esz[0][3] = 2; // unused
    // topic col-groups: k | v | qeff1 | qeff3
    pa.bias[1][0] = bk + 256;     pa.outB[1][0] = kv_t;                  pa.esz[1][0] = 1;
    pa.bias[1][1] = bv + 256;     pa.outB[1][1] = kv_t + 256;            pa.esz[1][1] = 1;
    pa.bias[1][2] = bq_eff + 256; pa.outB[1][2] = (unsigned char*)qhat1; pa.esz[1][2] = 2;
    pa.bias[1][3] = bq_eff + 768; pa.outB[1][3] = (unsigned char*)qhat3; pa.esz[1][3] = 2;
    // doc col-groups: qeff2 | qeff4
    pa.bias[2][0] = bq_eff + 512;  pa.outB[2][0] = (unsigned char*)qhat2; pa.esz[2][0] = 2;
    pa.bias[2][1] = bq_eff + 1024; pa.outB[2][1] = (unsigned char*)qhat4; pa.esz[2][1] = 2;
    pa.bias[2][2] = bq_eff;        pa.outB[2][2] = (unsigned char*)qhat2; pa.esz[2][2] = 2; // unused
    pa.bias[2][3] = bq_eff;        pa.outB[2][3] = (unsigned char*)qhat2; pa.esz[2][3] = 2; // unused
    pa.R[0] = cdiv(NW, 64); pa.C[0] = 3;    // 313 row-tiles x 3 col-groups
    pa.R[1] = cdiv(NT, 64); pa.C[1] = 4;    // 32 x 4
    pa.R[2] = cdiv(ND, 64); pa.C[2] = 2;    // 79 x 2
    int s0 = 8 * cdiv(pa.R[0], 8) * pa.C[0];   // 8*40*3 = 960
    int s1 = 8 * cdiv(pa.R[1], 8) * pa.C[1];   // 8*4*4  = 128
    int s2 = 8 * cdiv(pa.R[2], 8) * pa.C[2];   // 8*10*2 = 160
    pa.segBase[0] = 0; pa.segBase[1] = s0; pa.segBase[2] = s0 + s1; pa.segBase[3] = s0 + s1 + s2;
    pa.counts = counts; pa.offsets = offsets; pa.scanN = 34000;
    proj_all<<<pa.segBase[3] + 1, b256, 0, stream>>>(pa);
  }

  // ---- scatter ----
  scatter5<<<cdiv(370000, 256), b256, 0, stream>>>(dsc, offsets, cursor, ssrc);

  int NdstA[5] = {NW, NT, ND, NT, ND};

  // ---- fused attention + softmax + fp8 aggregation ----
  {
    AttArgs aa;
    aa.qh[0] = qhat0; aa.qh[1] = qhat1; aa.qh[2] = qhat2; aa.qh[3] = qhat3; aa.qh[4] = qhat4;
    aa.kv8[0] = aa.kv8[1] = aa.kv8[2] = kv_w; aa.kv8[3] = aa.kv8[4] = kv_t;
    unsigned short* aggs[5] = {aggr0, aggr1, aggr2, aggr3, aggr4};
    aa.ssrc = ssrc;
    int bc = 0;
    for (int r = 0; r < 5; r++) {
      aa.offs[r] = offsets + dsc.cbase[r];
      aa.agg[r] = aggs[r];
      aa.Ndst[r] = NdstA[r];
      aa.bcum[r] = bc; bc += cdiv(NdstA[r], 4);
    }
    aa.bcum[5] = bc;
    aa.pri = rel_pri;
    fused_att_agg<<<bc, b256, 0, stream>>>(aa);
  }

  // ---- msg transform + relu + cross-etype mean ----
  {
    MsgArgs ma;
    ma.aggA[0] = aggr0; ma.aggB[0] = nullptr;
    ma.fA[0] = wvp;             ma.fB[0] = wvp;
    ma.t[0] = t_word;  ma.scale[0] = 1.0f;  ma.N[0] = NW;
    ma.aggA[1] = aggr1; ma.aggB[1] = aggr3;
    ma.fA[1] = wvp + 8192;      ma.fB[1] = wvp + 3 * 8192;
    ma.t[1] = t_topic; ma.scale[1] = 0.5f;  ma.N[1] = NT;
    ma.aggA[2] = aggr2; ma.aggB[2] = aggr4;
    ma.fA[2] = wvp + 2 * 8192;  ma.fB[2] = wvp + 4 * 8192;
    ma.t[2] = t_doc;   ma.scale[2] = 0.5f;  ma.N[2] = ND;
    int bc = 0;
    for (int g = 0; g < 3; g++) { ma.bcum[g] = bc; bc += cdiv(ma.N[g], 64); }
    ma.bcum[3] = bc;
    msg_transform_all<<<bc, b256, 0, stream>>>(ma);
  }

  // ---- unified output GEMM + skip + LayerNorm ----
  {
    OutAll oa;
    oa.tA[0] = t_word;  oa.tA[1] = t_topic; oa.tA[2] = t_doc;
    oa.WT[0] = WTa; oa.WT[1] = WTa + 65536; oa.WT[2] = WTa + 131072;
    oa.ba[0] = ba; oa.ba[1] = ba + 256; oa.ba[2] = ba + 512;
    oa.feat[0] = feat_w; oa.feat[1] = feat_t; oa.feat[2] = feat_d;
    oa.gamma[0] = ln_scale; oa.gamma[1] = ln_scale + 256; oa.gamma[2] = ln_scale + 512;
    oa.beta[0] = ln_bias; oa.beta[1] = ln_bias + 256; oa.beta[2] = ln_bias + 512;
    oa.op[0] = out; oa.op[1] = out + (size_t)NW * 256; oa.op[2] = out + (size_t)(NW + NT) * 256;
    oa.M[0] = NW; oa.M[1] = NT; oa.M[2] = ND;
    int bc = 0;
    for (int g = 0; g < 3; g++) { oa.bcum[g] = bc; bc += cdiv(oa.M[g], 64); }
    oa.bcum[3] = bc;
    oa.skipv = skip;
    out_all_ln<<<bc, b256, 0, stream>>>(oa);
  }

  (void)in_sizes; (void)n_in; (void)out_size; (void)ws_size;
}

// Round 15
// 182.993 us; speedup vs baseline: 1.1400x; 1.1400x over previous
//
#include <hip/hip_runtime.h>

static constexpr int NW = 20000, NT = 2000, ND = 5000;
static constexpr int E_WW = 150000, E_WT = 80000, E_WD = 80000, E_TT = 20000, E_TD = 40000;

typedef short bf16x8 __attribute__((ext_vector_type(8)));
typedef float f32x4 __attribute__((ext_vector_type(4)));
typedef float f32x2 __attribute__((ext_vector_type(2)));

__device__ __forceinline__ unsigned short f2bf(float f) {
  union { float f; unsigned int u; } c; c.f = f;
  unsigned int u = c.u;
  u += 0x7fffu + ((u >> 16) & 1u);
  return (unsigned short)(u >> 16);
}
__device__ __forceinline__ float bf2f(unsigned short h) {
  union { unsigned int u; float f; } c; c.u = ((unsigned int)h) << 16; return c.f;
}
__device__ __forceinline__ bf16x8 pack8(float4 a, float4 b) {
  bf16x8 r;
  r[0] = (short)f2bf(a.x); r[1] = (short)f2bf(a.y); r[2] = (short)f2bf(a.z); r[3] = (short)f2bf(a.w);
  r[4] = (short)f2bf(b.x); r[5] = (short)f2bf(b.y); r[6] = (short)f2bf(b.z); r[7] = (short)f2bf(b.w);
  return r;
}
__device__ __forceinline__ unsigned char f2fp8(float x) {
  int p = __builtin_amdgcn_cvt_pk_fp8_f32(x, x, 0, false);
  return (unsigned char)(p & 0xff);
}

// ---------------- CSR descriptor ----------------
struct CsrDesc {
  const int* dst[5];
  const int* src[5];
  int E[5], N[5], cbase[5];
};

// ================= PREP mega-kernel: pack7 | wq_eff | pack_headw | hist =================
struct PrepArgs {
  const float* psrc[7]; unsigned short* pdst[7];
  const float* wq[5]; const float* bqp[5];
  unsigned short* qdst[5];
  float* beff;
  const float* att;
  const float* msg; unsigned short* wvp;
  CsrDesc dsc;
  int* counts;
  int bEff, bHw, bHist, bTot;
};
__global__ __launch_bounds__(256) void prep_kernel(PrepArgs a) {
  __shared__ float tile[32][33];
  int b = blockIdx.x;
  int tid = threadIdx.x;
  if (b < a.bEff) {
    int m = b >> 6, bk = ((b >> 3) & 7) * 32, bn = (b & 7) * 32;
    const float* W = a.psrc[m];
    unsigned short* WT = a.pdst[m];
    int tx = tid & 31, ty = tid >> 5;
#pragma unroll
    for (int i = 0; i < 32; i += 8)
      tile[ty + i][tx] = W[(size_t)(bk + ty + i) * 256 + bn + tx];
    __syncthreads();
#pragma unroll
    for (int i = 0; i < 32; i += 8)
      WT[(size_t)(bn + ty + i) * 256 + bk + tx] = f2bf(tile[tx][ty + i]);
  } else if (b < a.bHw) {
    int t = (b - a.bEff) * 256 + tid;
    if (t < 5 * 65536) {
      int r = t >> 16, rem = t & 65535;
      int n = rem >> 8, kk = rem & 255;
      int h = n >> 5, j = n & 31;
      const float* wrow = a.wq[r] + kk * 256 + h * 32;
      const float* arow = a.att + r * 8192 + h * 1024 + j * 32;
      float s = 0.f;
#pragma unroll
      for (int d = 0; d < 32; d += 4) {
        float4 wv = *(const float4*)(wrow + d);
        float4 av = *(const float4*)(arow + d);
        s += wv.x * av.x + wv.y * av.y + wv.z * av.z + wv.w * av.w;
      }
      a.qdst[r][n * 256 + kk] = f2bf(s);
    } else {
      int idx = t - 5 * 65536;
      if (idx < 1280) {
        int r = idx >> 8, n = idx & 255;
        int h = n >> 5, j = n & 31;
        const float* brow = a.bqp[r] + h * 32;
        const float* arow = a.att + r * 8192 + h * 1024 + j * 32;
        float s = 0.f;
#pragma unroll
        for (int d = 0; d < 32; d += 4) {
          float4 bv = *(const float4*)(brow + d);
          float4 av = *(const float4*)(arow + d);
          s += bv.x * av.x + bv.y * av.y + bv.z * av.z + bv.w * av.w;
        }
        a.beff[r * 256 + n] = s;
      }
    }
  } else if (b < a.bHist) {
    int t = (b - a.bHw) * 256 + tid;
    if (t < 5 * 8192) {
      int m = t >> 13, rem = t & 8191;
      int hc = rem >> 9, idx = rem & 511;
      int lane = idx >> 3, j = idx & 7;
      int h = hc >> 1, c = hc & 1;
      int k = (lane >> 4) * 8 + j, n = c * 16 + (lane & 15);
      a.wvp[t] = f2bf(a.msg[(size_t)m * 8192 + h * 1024 + k * 32 + n]);
    }
  } else {
    int t = (b - a.bHist) * 256 + tid;
    int r = 0, base = 0;
    while (r < 5 && t >= base + a.dsc.E[r]) { base += a.dsc.E[r]; r++; }
    if (r >= 5) return;
    int e = t - base;
    atomicAdd(a.counts + a.dsc.cbase[r] + a.dsc.dst[r][e], 1);
  }
}

// ================= projection GEMM v4: 64x64 tiles + XCD-aware swizzle ==================
struct ProjAll {
  const float* A[3];
  const unsigned short* WT[3];
  const float* bias[3][4];
  unsigned char* outB[3][4];
  int esz[3][4];
  int M[3], R[3], C[3], segBase[4];
  const int* counts; int* offsets; int scanN;   // embedded scan block
};
__global__ __launch_bounds__(256) void proj_all(ProjAll pa) {
  __shared__ unsigned short As[64 * 64];
  __shared__ unsigned short Bs[64 * 64];
  __shared__ int wpart2[4];
  __shared__ int carry2;
  const int tid = threadIdx.x;
  if ((int)blockIdx.x >= pa.segBase[3]) {
    int lane = tid & 63, w = tid >> 6;
    if (tid == 0) carry2 = 0;
    __syncthreads();
    const int N = pa.scanN;
    for (int base = 0; base < N; base += 1024) {
      int idx = base + tid * 4;
      int v0 = 0, v1 = 0, v2 = 0, v3 = 0;
      if (idx + 3 < N) {
        int4 t4 = *(const int4*)(pa.counts + idx);
        v0 = t4.x; v1 = t4.y; v2 = t4.z; v3 = t4.w;
      } else if (idx < N) {
        v0 = pa.counts[idx];
        if (idx + 1 < N) v1 = pa.counts[idx + 1];
        if (idx + 2 < N) v2 = pa.counts[idx + 2];
      }
      int ts = v0 + v1 + v2 + v3;
      int x = ts;
#pragma unroll
      for (int d = 1; d < 64; d <<= 1) {
        int t = __shfl_up(x, d, 64);
        if (lane >= d) x += t;
      }
      if (lane == 63) wpart2[w] = x;
      __syncthreads();
      if (tid == 0) {
        int s = 0;
#pragma unroll
        for (int j = 0; j < 4; j++) { int t = wpart2[j]; wpart2[j] = s; s += t; }
      }
      __syncthreads();
      int excl = carry2 + wpart2[w] + (x - ts);
      if (idx < N)     pa.offsets[idx]     = excl;
      if (idx + 1 < N) pa.offsets[idx + 1] = excl + v0;
      if (idx + 2 < N) pa.offsets[idx + 2] = excl + v0 + v1;
      if (idx + 3 < N) pa.offsets[idx + 3] = excl + v0 + v1 + v2;
      __syncthreads();
      if (tid == 255) carry2 = excl + ts;
      __syncthreads();
    }
    if (tid == 0) pa.offsets[N] = carry2;
    return;
  }
  int nt = 0;
  while (nt < 2 && (int)blockIdx.x >= pa.segBase[nt + 1]) nt++;
  int local = blockIdx.x - pa.segBase[nt];
  const int C = pa.C[nt];
  const int xcd = local & 7, slot = local >> 3;
  const int rt = xcd + 8 * (slot / C);
  const int bnb = slot % C;
  if (rt >= pa.R[nt]) return;
  const int bm = rt * 64, bn = bnb * 64;
  const float* A = pa.A[nt];
  const unsigned short* WT = pa.WT[nt];
  const int M = pa.M[nt];
  const int wave = tid >> 6, lane = tid & 63;
  f32x4 acc[4] = {};
  const int ar = wave * 16 + (lane & 15);
  const int swz = lane & 7;
  for (int k0 = 0; k0 < 256; k0 += 64) {
#pragma unroll
    for (int i = 0; i < 2; i++) {
      int c = tid + i * 256;
      int row = c >> 3, sl = c & 7;
      int srow = bm + row;
      float4 a0 = make_float4(0.f, 0.f, 0.f, 0.f), a1 = a0;
      if (srow < M) {
        a0 = *(const float4*)(A + (size_t)srow * 256 + k0 + sl * 8);
        a1 = *(const float4*)(A + (size_t)srow * 256 + k0 + sl * 8 + 4);
      }
      *(bf16x8*)&As[row * 64 + (sl ^ (row & 7)) * 8] = pack8(a0, a1);
      bf16x8 bv = *(const bf16x8*)(WT + (size_t)(bn + row) * 256 + k0 + sl * 8);
      *(bf16x8*)&Bs[row * 64 + (sl ^ (row & 7)) * 8] = bv;
    }
    __syncthreads();
#pragma unroll
    for (int kk = 0; kk < 2; kk++) {
      int slot2 = kk * 4 + (lane >> 4);
      bf16x8 av = *(const bf16x8*)&As[ar * 64 + ((slot2 ^ swz) * 8)];
#pragma unroll
      for (int nf = 0; nf < 4; nf++) {
        int br = nf * 16 + (lane & 15);
        bf16x8 bv = *(const bf16x8*)&Bs[br * 64 + ((slot2 ^ swz) * 8)];
        acc[nf] = __builtin_amdgcn_mfma_f32_16x16x32_bf16(av, bv, acc[nf], 0, 0, 0);
      }
    }
    __syncthreads();
  }
  const int col = lane & 15;
  const int seg = bnb >> 2;
  const float* bias = pa.bias[nt][seg];
  unsigned char* outB = pa.outB[nt][seg];
  const int esz = pa.esz[nt][seg];
  const int cbase = (bnb & 3) * 64;
#pragma unroll
  for (int nf = 0; nf < 4; nf++) {
    float bsv = bias[cbase + nf * 16 + col];
    int idx = cbase + nf * 16 + col;
#pragma unroll
    for (int rr = 0; rr < 4; rr++) {
      int row = bm + wave * 16 + (lane >> 4) * 4 + rr;
      if (row < M) {
        float v = acc[nf][rr] + bsv;
        if (esz == 2) *(unsigned short*)(outB + (size_t)row * 512 + idx * 2) = f2bf(v);
        else          outB[(size_t)row * 512 + idx] = f2fp8(v);
      }
    }
  }
}

// ================= scatter =================
__global__ void scatter5(CsrDesc d, const int* __restrict__ offsets, int* __restrict__ cursor,
                         int* __restrict__ ssrc) {
  int t = blockIdx.x * blockDim.x + threadIdx.x;
  int r = 0, base = 0;
  while (r < 5 && t >= base + d.E[r]) { base += d.E[r]; r++; }
  if (r >= 5) return;
  int e = t - base;
  int dn = d.dst[r][e];
  int pos = offsets[d.cbase[r] + dn] + atomicAdd(cursor + d.cbase[r] + dn, 1);
  ssrc[pos] = d.src[r][e];
}

// ================= fused attention + online softmax + fp8 k/v aggregation =================
struct AttArgs {
  const unsigned short* qh[5]; const unsigned char* kv8[5];
  const int* offs[5]; unsigned short* agg[5];
  const int* ssrc;
  const float* pri;
  int bcum[6]; int Ndst[5];
};
__global__ __launch_bounds__(256) void fused_att_agg(AttArgs a) {
  int r = 0;
  while (r < 4 && (int)blockIdx.x >= a.bcum[r + 1]) r++;
  int wave = threadIdx.x >> 6, lane = threadIdx.x & 63;
  int node = (blockIdx.x - a.bcum[r]) * 4 + wave;
  if (node >= a.Ndst[r]) return;
  const unsigned short* qh = a.qh[r];
  const unsigned char* kvb = a.kv8[r];
  const int* ssrc = a.ssrc;
  const int* offs = a.offs[r];
  int h = lane >> 3;
  float prih = a.pri[r * 8 + h] * 0.17677669529663687f;  // pri/sqrt(32)
  int r0 = offs[node], r1 = offs[node + 1];
  float4 acc = make_float4(0.f, 0.f, 0.f, 0.f);
  if (r0 < r1) {
    ushort4 qv = *(const ushort4*)(qh + (size_t)node * 256 + lane * 4);
    float q0 = bf2f(qv.x), q1 = bf2f(qv.y), q2 = bf2f(qv.z), q3 = bf2f(qv.w);
    float m = -1e30f, s = 0.f;
    for (int i = r0; i < r1; i += 2) {
      int sA = ssrc[i];
      bool two = (i + 1 < r1);
      int sB = two ? ssrc[i + 1] : sA;
      const unsigned char* pA = kvb + (size_t)sA * 512 + lane * 4;
      const unsigned char* pB = kvb + (size_t)sB * 512 + lane * 4;
      unsigned int kuA = *(const unsigned int*)pA;
      unsigned int kuB = *(const unsigned int*)pB;
      unsigned int vuA = *(const unsigned int*)(pA + 256);
      unsigned int vuB = *(const unsigned int*)(pB + 256);
      f32x2 ka01 = __builtin_amdgcn_cvt_pk_f32_fp8((int)kuA, false);
      f32x2 ka23 = __builtin_amdgcn_cvt_pk_f32_fp8((int)kuA, true);
      f32x2 kb01 = __builtin_amdgcn_cvt_pk_f32_fp8((int)kuB, false);
      f32x2 kb23 = __builtin_amdgcn_cvt_pk_f32_fp8((int)kuB, true);
      float dA = q0 * ka01[0] + q1 * ka01[1] + q2 * ka23[0] + q3 * ka23[1];
      float dB = q0 * kb01[0] + q1 * kb01[1] + q2 * kb23[0] + q3 * kb23[1];
      dA += __shfl_xor(dA, 1, 64); dB += __shfl_xor(dB, 1, 64);
      dA += __shfl_xor(dA, 2, 64); dB += __shfl_xor(dB, 2, 64);
      dA += __shfl_xor(dA, 4, 64); dB += __shfl_xor(dB, 4, 64);
      float lA = dA * prih;
      float lB = two ? dB * prih : -1e30f;
      float mn = fmaxf(m, fmaxf(lA, lB));
      float sc = __expf(m - mn);
      float wA = __expf(lA - mn);
      float wB = __expf(lB - mn);
      m = mn;
      s = s * sc + wA + wB;
      f32x2 va01 = __builtin_amdgcn_cvt_pk_f32_fp8((int)vuA, false);
      f32x2 va23 = __builtin_amdgcn_cvt_pk_f32_fp8((int)vuA, true);
      f32x2 vb01 = __builtin_amdgcn_cvt_pk_f32_fp8((int)vuB, false);
      f32x2 vb23 = __builtin_amdgcn_cvt_pk_f32_fp8((int)vuB, true);
      acc.x = acc.x * sc + wA * va01[0] + wB * vb01[0];
      acc.y = acc.y * sc + wA * va01[1] + wB * vb01[1];
      acc.z = acc.z * sc + wA * va23[0] + wB * vb23[0];
      acc.w = acc.w * sc + wA * va23[1] + wB * vb23[1];
    }
    float inv = 1.f / fmaxf(s, 1e-9f);
    acc.x *= inv; acc.y *= inv; acc.z *= inv; acc.w *= inv;
  }
  ushort4 o;
  o.x = f2bf(acc.x); o.y = f2bf(acc.y); o.z = f2bf(acc.z); o.w = f2bf(acc.w);
  *(ushort4*)(a.agg[r] + (size_t)node * 256 + lane * 4) = o;
}

// ================= FUSED: msg transform + relu/mean + out GEMM + skip + LayerNorm =======
// One block per 64-row tile. Phase 1: per-head msg MFMA -> t tile in LDS (A-frag layout).
// Phase 2: out GEMM (Bs per k0) + skip-blend + LN epilogue.
struct OutAll {
  const unsigned short* aggA[3]; const unsigned short* aggB[3];
  const unsigned short* fA[3]; const unsigned short* fB[3];
  float scale[3];
  const unsigned short* WT[3];
  const float* ba[3]; const float* feat[3];
  const float* gamma[3]; const float* beta[3];
  float* op[3];
  int M[3], bcum[4];
  const float* skipv;
};
__global__ __launch_bounds__(256) void out_all_fused(OutAll oa) {
  __shared__ unsigned short As[64 * 256];   // 32 KB: t tile, A-frag swizzled
  __shared__ unsigned short Bs[256 * 64];   // 32 KB
  int g = 0;
  while (g < 2 && (int)blockIdx.x >= oa.bcum[g + 1]) g++;
  const int bm = (blockIdx.x - oa.bcum[g]) * 64;
  const int M = oa.M[g];
  const int tid = threadIdx.x, wave = tid >> 6, lane = tid & 63;
  // ---- phase 1: msg transform for this block's 64 rows -> As ----
  {
    const unsigned short* aggA = oa.aggA[g];
    const unsigned short* aggB = oa.aggB[g];
    const unsigned short* fA = oa.fA[g];
    const unsigned short* fB = oa.fB[g];
    const float scale = oa.scale[g];
    int arow = bm + wave * 16 + (lane & 15);
    bool valid = arow < M;
    int kofs = (lane >> 4) * 8;
    f32x4 z{};
#pragma unroll
    for (int h = 0; h < 8; h++) {
      bf16x8 aA{}, aB{};
      if (valid) {
        aA = *(const bf16x8*)(aggA + (size_t)arow * 256 + h * 32 + kofs);
        if (aggB) aB = *(const bf16x8*)(aggB + (size_t)arow * 256 + h * 32 + kofs);
      }
#pragma unroll
      for (int c = 0; c < 2; c++) {
        bf16x8 bA = *(const bf16x8*)(fA + ((h * 2 + c) * 64 + lane) * 8);
        f32x4 oA = __builtin_amdgcn_mfma_f32_16x16x32_bf16(aA, bA, z, 0, 0, 0);
        f32x4 oB = z;
        if (aggB) {
          bf16x8 bB = *(const bf16x8*)(fB + ((h * 2 + c) * 64 + lane) * 8);
          oB = __builtin_amdgcn_mfma_f32_16x16x32_bf16(aB, bB, z, 0, 0, 0);
        }
        int colc = h * 32 + c * 16 + (lane & 15);
        int slotc = colc >> 3, jc = colc & 7;
#pragma unroll
        for (int rr = 0; rr < 4; rr++) {
          int lrow = wave * 16 + (lane >> 4) * 4 + rr;
          float v = fmaxf(oA[rr], 0.f) + fmaxf(oB[rr], 0.f);
          As[lrow * 256 + ((slotc ^ (lrow & 7)) * 8) + jc] = f2bf(v * scale);
        }
      }
    }
  }
  __syncthreads();
  // ---- phase 2: out GEMM (As persistent, Bs per k0) ----
  const unsigned short* WT = oa.WT[g];
  f32x4 acc[16] = {};
  const int ar = wave * 16 + (lane & 15);
  const int swz = lane & 7;
  for (int k0 = 0; k0 < 256; k0 += 64) {
    if (k0) __syncthreads();   // protect Bs reuse
#pragma unroll
    for (int i = 0; i < 8; i++) {
      int c = tid + i * 256;
      int row = c >> 3, sl = c & 7;
      bf16x8 bv = *(const bf16x8*)(WT + (size_t)row * 256 + k0 + sl * 8);
      *(bf16x8*)&Bs[row * 64 + (sl ^ (row & 7)) * 8] = bv;
    }
    __syncthreads();
#pragma unroll
    for (int kk = 0; kk < 2; kk++) {
      int slot = kk * 4 + (lane >> 4);
      int gslot = (k0 >> 3) + slot;
      bf16x8 av = *(const bf16x8*)&As[ar * 256 + ((gslot ^ swz) * 8)];
#pragma unroll
      for (int nf = 0; nf < 16; nf++) {
        int br = nf * 16 + (lane & 15);
        bf16x8 bv = *(const bf16x8*)&Bs[br * 64 + ((slot ^ swz) * 8)];
        acc[nf] = __builtin_amdgcn_mfma_f32_16x16x32_bf16(av, bv, acc[nf], 0, 0, 0);
      }
    }
  }
  // ---- epilogue: bias + skip-blend + LayerNorm ----
  const int c16 = lane & 15;
  float a_skip = 1.f / (1.f + __expf(-oa.skipv[g]));
  float one_m = 1.f - a_skip;
  const float* gamma = oa.gamma[g];
  const float* beta = oa.beta[g];
  const float* ba = oa.ba[g];
  const float* feat = oa.feat[g];
  float* outp = oa.op[g];
  float gg[16], bb[16], bia[16];
#pragma unroll
  for (int nf = 0; nf < 16; nf++) {
    gg[nf] = gamma[nf * 16 + c16];
    bb[nf] = beta[nf * 16 + c16];
    bia[nf] = ba[nf * 16 + c16];
  }
#pragma unroll
  for (int rr = 0; rr < 4; rr++) {
    int row = bm + wave * 16 + (lane >> 4) * 4 + rr;
    bool valid = row < M;
#pragma unroll
    for (int nf = 0; nf < 16; nf++) {
      float fv = valid ? feat[(size_t)row * 256 + nf * 16 + c16] : 0.f;
      acc[nf][rr] = (acc[nf][rr] + bia[nf]) * a_skip + fv * one_m;
    }
    float p = 0.f;
#pragma unroll
    for (int nf = 0; nf < 16; nf++) p += acc[nf][rr];
    p += __shfl_xor(p, 1, 16); p += __shfl_xor(p, 2, 16);
    p += __shfl_xor(p, 4, 16); p += __shfl_xor(p, 8, 16);
    float mu = p * (1.f / 256.f);
    float qv = 0.f;
#pragma unroll
    for (int nf = 0; nf < 16; nf++) { float dd = acc[nf][rr] - mu; qv += dd * dd; }
    qv += __shfl_xor(qv, 1, 16); qv += __shfl_xor(qv, 2, 16);
    qv += __shfl_xor(qv, 4, 16); qv += __shfl_xor(qv, 8, 16);
    float rstd = rsqrtf(qv * (1.f / 256.f) + 1e-5f);
    if (valid) {
#pragma unroll
      for (int nf = 0; nf < 16; nf++)
        outp[(size_t)row * 256 + nf * 16 + c16] = (acc[nf][rr] - mu) * rstd * gg[nf] + bb[nf];
    }
  }
}

extern "C" void kernel_launch(void* const* d_in, const int* in_sizes, int n_in,
                              void* d_out, int out_size, void* d_ws, size_t ws_size,
                              hipStream_t stream) {
  const float* feat_w = (const float*)d_in[0];
  const float* feat_t = (const float*)d_in[1];
  const float* feat_d = (const float*)d_in[2];
  const float* Wk = (const float*)d_in[3];
  const float* bk = (const float*)d_in[4];
  const float* Wq = (const float*)d_in[5];
  const float* bq = (const float*)d_in[6];
  const float* Wv = (const float*)d_in[7];
  const float* bv = (const float*)d_in[8];
  const float* Wa = (const float*)d_in[9];
  const float* ba = (const float*)d_in[10];
  const float* ln_scale = (const float*)d_in[11];
  const float* ln_bias = (const float*)d_in[12];
  const float* skip = (const float*)d_in[13];
  const float* rel_pri = (const float*)d_in[14];
  const float* rel_att = (const float*)d_in[15];
  const float* rel_msg = (const float*)d_in[16];
  const int* src_ww = (const int*)d_in[17];
  const int* dst_ww = (const int*)d_in[18];
  const int* src_wt = (const int*)d_in[19];
  const int* dst_wt = (const int*)d_in[20];
  const int* src_wd = (const int*)d_in[21];
  const int* dst_wd = (const int*)d_in[22];
  const int* src_tt = (const int*)d_in[23];
  const int* dst_tt = (const int*)d_in[24];
  const int* src_td = (const int*)d_in[25];
  const int* dst_td = (const int*)d_in[26];
  float* out = (float*)d_out;
  float* ws = (float*)d_ws;

  // ---- workspace (sizes in FLOAT units) ----
  size_t off = 0;
  auto allocF = [&](size_t nf) { float* p = ws + off; off += nf; return p; };
  unsigned char* kv_w = (unsigned char*)allocF(2560000);   // [20000][512B] fp8 k|v
  unsigned char* kv_t = (unsigned char*)allocF(256000);    // [2000][512B]
  unsigned short* qhat0 = (unsigned short*)allocF(2560000);
  unsigned short* qhat1 = (unsigned short*)allocF(256000);
  unsigned short* qhat2 = (unsigned short*)allocF(640000);
  unsigned short* qhat3 = (unsigned short*)allocF(256000);
  unsigned short* qhat4 = (unsigned short*)allocF(640000);
  unsigned short* aggr0 = (unsigned short*)allocF(2560000);
  unsigned short* aggr1 = (unsigned short*)allocF(256000);
  unsigned short* aggr2 = (unsigned short*)allocF(640000);
  unsigned short* aggr3 = (unsigned short*)allocF(256000);
  unsigned short* aggr4 = (unsigned short*)allocF(640000);
  unsigned short* WTw = (unsigned short*)allocF(98304);   // [768][256]:  qeff0 | k | v
  unsigned short* WTt = (unsigned short*)allocF(131072);  // [1024][256]: k | v | qeff1 | qeff3
  unsigned short* WTd = (unsigned short*)allocF(65536);   // [512][256]:  qeff2 | qeff4
  unsigned short* WTa = (unsigned short*)allocF(98304);   // 3 x 256x256
  unsigned short* wvp = (unsigned short*)allocF(20480);   // msg frag-packed
  float* bq_eff = allocF(1280);                           // 5 x 256 f32
  int* counts  = (int*)allocF(34000);
  int* cursor  = (int*)allocF(34000);
  int* offsets = (int*)allocF(34004);
  int* ssrc    = (int*)allocF(370000);

  dim3 b256(256);
  auto cdiv = [](int a, int b) { return (a + b - 1) / b; };

  // ---- CSR descriptor ----
  CsrDesc dsc;
  dsc.dst[0] = dst_ww; dsc.dst[1] = dst_wt; dsc.dst[2] = dst_wd; dsc.dst[3] = dst_tt; dsc.dst[4] = dst_td;
  dsc.src[0] = src_ww; dsc.src[1] = src_wt; dsc.src[2] = src_wd; dsc.src[3] = src_tt; dsc.src[4] = src_td;
  int Es[5] = {E_WW, E_WT, E_WD, E_TT, E_TD};
  int Ns[5] = {NW, NT, ND, NT, ND};
  int cb = 0;
  for (int r = 0; r < 5; r++) {
    dsc.E[r] = Es[r]; dsc.N[r] = Ns[r]; dsc.cbase[r] = cb;
    cb += Ns[r];
  }

  hipMemsetAsync(counts, 0, (size_t)68000 * sizeof(int), stream);  // counts + cursor

  // ---- prep mega-kernel ----
  {
    PrepArgs pr;
    pr.psrc[0] = Wk;           pr.pdst[0] = WTw + 65536;    // word k
    pr.psrc[1] = Wv;           pr.pdst[1] = WTw + 131072;   // word v
    pr.psrc[2] = Wk + 65536;   pr.pdst[2] = WTt;            // topic k
    pr.psrc[3] = Wv + 65536;   pr.pdst[3] = WTt + 65536;    // topic v
    pr.psrc[4] = Wa;           pr.pdst[4] = WTa;
    pr.psrc[5] = Wa + 65536;   pr.pdst[5] = WTa + 65536;
    pr.psrc[6] = Wa + 131072;  pr.pdst[6] = WTa + 131072;
    pr.wq[0] = Wq;           pr.bqp[0] = bq;        pr.qdst[0] = WTw;            // ww
    pr.wq[1] = Wq + 65536;   pr.bqp[1] = bq + 256;  pr.qdst[1] = WTt + 131072;   // wt
    pr.wq[2] = Wq + 131072;  pr.bqp[2] = bq + 512;  pr.qdst[2] = WTd;            // wd
    pr.wq[3] = Wq + 65536;   pr.bqp[3] = bq + 256;  pr.qdst[3] = WTt + 196608;   // tt
    pr.wq[4] = Wq + 131072;  pr.bqp[4] = bq + 512;  pr.qdst[4] = WTd + 65536;    // td
    pr.beff = bq_eff;
    pr.att = rel_att;
    pr.msg = rel_msg; pr.wvp = wvp;
    pr.dsc = dsc; pr.counts = counts;
    int nPack = 7 * 64;                         // 448
    int nEff  = cdiv(5 * 65536 + 1280, 256);    // 1285
    int nHw   = cdiv(5 * 8192, 256);            // 160
    int nHist = cdiv(370000, 256);              // 1446
    pr.bEff  = nPack;
    pr.bHw   = nPack + nEff;
    pr.bHist = nPack + nEff + nHw;
    pr.bTot  = nPack + nEff + nHw + nHist;
    prep_kernel<<<pr.bTot, b256, 0, stream>>>(pr);
  }

  // ---- projections v4 (64x64 tiles, XCD swizzle, + scan block) ----
  {
    ProjAll pa;
    pa.A[0] = feat_w; pa.A[1] = feat_t; pa.A[2] = feat_d;
    pa.WT[0] = WTw;   pa.WT[1] = WTt;   pa.WT[2] = WTd;
    pa.M[0] = NW; pa.M[1] = NT; pa.M[2] = ND;
    // word segments: qeff0 (bf16) | k (fp8) | v (fp8)
    pa.bias[0][0] = bq_eff;       pa.outB[0][0] = (unsigned char*)qhat0; pa.esz[0][0] = 2;
    pa.bias[0][1] = bk;           pa.outB[0][1] = kv_w;                  pa.esz[0][1] = 1;
    pa.bias[0][2] = bv;           pa.outB[0][2] = kv_w + 256;            pa.esz[0][2] = 1;
    pa.bias[0][3] = bq_eff;       pa.outB[0][3] = (unsigned char*)qhat0; pa.esz[0][3] = 2; // unused
    // topic segments: k | v | qeff1 | qeff3
    pa.bias[1][0] = bk + 256;     pa.outB[1][0] = kv_t;                  pa.esz[1][0] = 1;
    pa.bias[1][1] = bv + 256;     pa.outB[1][1] = kv_t + 256;            pa.esz[1][1] = 1;
    pa.bias[1][2] = bq_eff + 256; pa.outB[1][2] = (unsigned char*)qhat1; pa.esz[1][2] = 2;
    pa.bias[1][3] = bq_eff + 768; pa.outB[1][3] = (unsigned char*)qhat3; pa.esz[1][3] = 2;
    // doc segments: qeff2 | qeff4
    pa.bias[2][0] = bq_eff + 512;  pa.outB[2][0] = (unsigned char*)qhat2; pa.esz[2][0] = 2;
    pa.bias[2][1] = bq_eff + 1024; pa.outB[2][1] = (unsigned char*)qhat4; pa.esz[2][1] = 2;
    pa.bias[2][2] = bq_eff;        pa.outB[2][2] = (unsigned char*)qhat2; pa.esz[2][2] = 2; // unused
    pa.bias[2][3] = bq_eff;        pa.outB[2][3] = (unsigned char*)qhat2; pa.esz[2][3] = 2; // unused
    pa.R[0] = cdiv(NW, 64); pa.C[0] = 12;   // 313 x 12
    pa.R[1] = cdiv(NT, 64); pa.C[1] = 16;   // 32 x 16
    pa.R[2] = cdiv(ND, 64); pa.C[2] = 8;    // 79 x 8
    int s0 = 8 * cdiv(pa.R[0], 8) * pa.C[0];
    int s1 = 8 * cdiv(pa.R[1], 8) * pa.C[1];
    int s2 = 8 * cdiv(pa.R[2], 8) * pa.C[2];
    pa.segBase[0] = 0; pa.segBase[1] = s0; pa.segBase[2] = s0 + s1; pa.segBase[3] = s0 + s1 + s2;
    pa.counts = counts; pa.offsets = offsets; pa.scanN = 34000;
    proj_all<<<pa.segBase[3] + 1, b256, 0, stream>>>(pa);
  }

  // ---- scatter ----
  scatter5<<<cdiv(370000, 256), b256, 0, stream>>>(dsc, offsets, cursor, ssrc);

  int NdstA[5] = {NW, NT, ND, NT, ND};

  // ---- fused attention + softmax + fp8 aggregation ----
  {
    AttArgs aa;
    aa.qh[0] = qhat0; aa.qh[1] = qhat1; aa.qh[2] = qhat2; aa.qh[3] = qhat3; aa.qh[4] = qhat4;
    aa.kv8[0] = aa.kv8[1] = aa.kv8[2] = kv_w; aa.kv8[3] = aa.kv8[4] = kv_t;
    unsigned short* aggs[5] = {aggr0, aggr1, aggr2, aggr3, aggr4};
    aa.ssrc = ssrc;
    int bc = 0;
    for (int r = 0; r < 5; r++) {
      aa.offs[r] = offsets + dsc.cbase[r];
      aa.agg[r] = aggs[r];
      aa.Ndst[r] = NdstA[r];
      aa.bcum[r] = bc; bc += cdiv(NdstA[r], 4);
    }
    aa.bcum[5] = bc;
    aa.pri = rel_pri;
    fused_att_agg<<<bc, b256, 0, stream>>>(aa);
  }

  // ---- fused msg + output GEMM + skip + LayerNorm ----
  {
    OutAll oa;
    oa.aggA[0] = aggr0; oa.aggB[0] = nullptr;
    oa.fA[0] = wvp;             oa.fB[0] = wvp;
    oa.scale[0] = 1.0f;
    oa.aggA[1] = aggr1; oa.aggB[1] = aggr3;
    oa.fA[1] = wvp + 8192;      oa.fB[1] = wvp + 3 * 8192;
    oa.scale[1] = 0.5f;
    oa.aggA[2] = aggr2; oa.aggB[2] = aggr4;
    oa.fA[2] = wvp + 2 * 8192;  oa.fB[2] = wvp + 4 * 8192;
    oa.scale[2] = 0.5f;
    oa.WT[0] = WTa; oa.WT[1] = WTa + 65536; oa.WT[2] = WTa + 131072;
    oa.ba[0] = ba; oa.ba[1] = ba + 256; oa.ba[2] = ba + 512;
    oa.feat[0] = feat_w; oa.feat[1] = feat_t; oa.feat[2] = feat_d;
    oa.gamma[0] = ln_scale; oa.gamma[1] = ln_scale + 256; oa.gamma[2] = ln_scale + 512;
    oa.beta[0] = ln_bias; oa.beta[1] = ln_bias + 256; oa.beta[2] = ln_bias + 512;
    oa.op[0] = out; oa.op[1] = out + (size_t)NW * 256; oa.op[2] = out + (size_t)(NW + NT) * 256;
    oa.M[0] = NW; oa.M[1] = NT; oa.M[2] = ND;
    int bc = 0;
    for (int g = 0; g < 3; g++) { oa.bcum[g] = bc; bc += cdiv(oa.M[g], 64); }
    oa.bcum[3] = bc;
    oa.skipv = skip;
    out_all_fused<<<bc, b256, 0, stream>>>(oa);
  }

  (void)in_sizes; (void)n_in; (void)out_size; (void)ws_size;
}